// Round 1
// baseline (1305.240 us; speedup 1.0000x reference)
//
#include <hip/hip_runtime.h>
#include <hip/hip_bf16.h>
#include <stdint.h>

// Problem constants (shapes fixed by the reference)
#define DIM 1024
#define NH 16
#define HD 64
#define S_ORIG 8704
#define WIN 512          // L * WINDOW = 256*2

typedef __attribute__((ext_vector_type(8))) short short8;
typedef __attribute__((ext_vector_type(4))) float f32x4;

__device__ __forceinline__ float bf2f(unsigned short u) {
    return __uint_as_float(((unsigned int)u) << 16);
}
__device__ __forceinline__ unsigned short f2bf(float f) {
    unsigned int x = __float_as_uint(f);
    unsigned int r = x + 0x7fffu + ((x >> 16) & 1u);   // RNE
    return (unsigned short)(r >> 16);
}

// ---------------- fp32 -> bf16 convert (x) ----------------
__global__ __launch_bounds__(256) void cvt_x(const float* __restrict__ x,
                                             unsigned short* __restrict__ xb) {
    int i = (blockIdx.x * 256 + threadIdx.x) * 4;   // total = 8704*1024, exact
    float4 v = *(const float4*)(x + i);
    ushort4 o;
    o.x = f2bf(v.x); o.y = f2bf(v.y); o.z = f2bf(v.z); o.w = f2bf(v.w);
    *(ushort4*)(xb + i) = o;
}

// ---------------- weight transpose + convert: Wt[n][k] = bf16(W[k][n]) ----------------
__global__ __launch_bounds__(256) void transpose_w(const float* __restrict__ w0,
                                                   const float* __restrict__ w1,
                                                   const float* __restrict__ w2,
                                                   const float* __restrict__ w3,
                                                   unsigned short* __restrict__ wt) {
    __shared__ float ts[64][65];
    const int z = blockIdx.z;
    const float* w = z == 0 ? w0 : z == 1 ? w1 : z == 2 ? w2 : w3;
    unsigned short* o = wt + (size_t)z * DIM * DIM;
    const int kb = blockIdx.x * 64, nb = blockIdx.y * 64;
    const int t = threadIdx.x, c = t & 63, r4 = t >> 6;
#pragma unroll
    for (int rr = 0; rr < 16; rr++) {
        int row = rr * 4 + r4;
        ts[row][c] = w[(size_t)(kb + row) * DIM + nb + c];
    }
    __syncthreads();
#pragma unroll
    for (int rr = 0; rr < 16; rr++) {
        int nl = rr * 4 + r4;
        o[(size_t)(nb + nl) * DIM + kb + c] = f2bf(ts[c][nl]);
    }
}

// ---------------- bf16 MFMA GEMM: C[M,N] = A[M,K] * Bt[N,K]^T + bias ----------------
// 128x128 tile, 4 waves (each 64x64 as 4x4 grid of 16x16x32 MFMA), BK=32.
// OUTF32=0: bf16 out plane z (h buffer [3][S][D]); OUTF32=1: fp32 out (d_out).
template <int OUTF32>
__global__ __launch_bounds__(256) void gemm_bf16(const unsigned short* __restrict__ A,
                                                 const unsigned short* __restrict__ Bt,
                                                 const float* __restrict__ b0,
                                                 const float* __restrict__ b1,
                                                 const float* __restrict__ b2,
                                                 void* __restrict__ Cout) {
    __shared__ __align__(16) unsigned short As[128 * 32];
    __shared__ __align__(16) unsigned short Bs[128 * 32];
    const int z = blockIdx.z;
    const unsigned short* B = Bt + (size_t)z * DIM * DIM;
    const float* bias = z == 0 ? b0 : (z == 1 ? b1 : b2);
    const int m0 = blockIdx.y * 128, n0 = blockIdx.x * 128;
    const int tid = threadIdx.x;
    const int lane = tid & 63, wv = tid >> 6;
    const int wr = wv >> 1, wc = wv & 1;
    const int quad = lane >> 4, r = lane & 15;

    f32x4 acc[4][4];
#pragma unroll
    for (int i = 0; i < 4; i++)
#pragma unroll
        for (int j = 0; j < 4; j++)
#pragma unroll
            for (int t4 = 0; t4 < 4; t4++) acc[i][j][t4] = 0.0f;

    const unsigned short* a_base = A + (size_t)m0 * DIM;
    const unsigned short* b_base = B + (size_t)n0 * DIM;
    // staging chunks: chunk c (16B = 8 bf16): row = c>>2, col = (c&3)*8
    const int c0 = tid, c1 = 256 + tid;
    const int r0 = c0 >> 2, o0 = (c0 & 3) * 8;
    const int r1 = c1 >> 2, o1 = (c1 & 3) * 8;

    for (int k0 = 0; k0 < DIM; k0 += 32) {
        int4 a0 = *(const int4*)(a_base + (size_t)r0 * DIM + k0 + o0);
        int4 a1 = *(const int4*)(a_base + (size_t)r1 * DIM + k0 + o1);
        int4 g0 = *(const int4*)(b_base + (size_t)r0 * DIM + k0 + o0);
        int4 g1 = *(const int4*)(b_base + (size_t)r1 * DIM + k0 + o1);
        __syncthreads();   // protect LDS from previous iteration's readers
        *(int4*)&As[c0 * 8] = a0;
        *(int4*)&As[c1 * 8] = a1;
        *(int4*)&Bs[c0 * 8] = g0;
        *(int4*)&Bs[c1 * 8] = g1;
        __syncthreads();
        short8 af[4], bfr[4];
#pragma unroll
        for (int i = 0; i < 4; i++)
            af[i] = *(const short8*)&As[(wr * 64 + i * 16 + r) * 32 + quad * 8];
#pragma unroll
        for (int j = 0; j < 4; j++)
            bfr[j] = *(const short8*)&Bs[(wc * 64 + j * 16 + r) * 32 + quad * 8];
#pragma unroll
        for (int i = 0; i < 4; i++)
#pragma unroll
            for (int j = 0; j < 4; j++)
                acc[i][j] = __builtin_amdgcn_mfma_f32_16x16x32_bf16(af[i], bfr[j], acc[i][j], 0, 0, 0);
    }

    // epilogue: C/D layout col = lane&15, row = quad*4 + reg
#pragma unroll
    for (int i = 0; i < 4; i++) {
        const int row = m0 + wr * 64 + i * 16 + quad * 4;
#pragma unroll
        for (int j = 0; j < 4; j++) {
            const int col = n0 + wc * 64 + j * 16 + r;
            const float bvl = bias[col];
#pragma unroll
            for (int t4 = 0; t4 < 4; t4++) {
                float vv = acc[i][j][t4] + bvl;
                if (OUTF32) {
                    ((float*)Cout)[(size_t)(row + t4) * DIM + col] = vv;
                } else {
                    ((unsigned short*)Cout)[(size_t)z * S_ORIG * DIM + (size_t)(row + t4) * DIM + col] = f2bf(vv);
                }
            }
        }
    }
}

// ---------------- fused RMSNorm + RoPE (in-place on bf16 plane) ----------------
__global__ __launch_bounds__(256) void norm_rope(unsigned short* __restrict__ hq,
                                                 unsigned short* __restrict__ hk,
                                                 const float* __restrict__ gq,
                                                 const float* __restrict__ gk,
                                                 const float* __restrict__ fcos,
                                                 const float* __restrict__ fsin) {
    const int srow = blockIdx.x;
    const int z = blockIdx.y;
    unsigned short* h = z == 0 ? hq : hk;
    const float* g = z == 0 ? gq : gk;
    const int tid = threadIdx.x;
    const int base = tid * 4;                 // 4 elems = 2 rope pairs per thread
    unsigned short* hp = h + (size_t)srow * DIM;

    ushort4 raw = *(const ushort4*)(hp + base);
    float v0 = bf2f(raw.x), v1 = bf2f(raw.y), v2 = bf2f(raw.z), v3 = bf2f(raw.w);
    float ss = v0 * v0 + v1 * v1 + v2 * v2 + v3 * v3;
#pragma unroll
    for (int off = 1; off < 64; off <<= 1) ss += __shfl_xor(ss, off, 64);
    __shared__ float red[4];
    if ((tid & 63) == 0) red[tid >> 6] = ss;
    __syncthreads();
    ss = red[0] + red[1] + red[2] + red[3];
    const float rinv = rsqrtf(ss * (1.0f / DIM) + 1e-6f);

    float4 gv = *(const float4*)(g + base);
    v0 *= rinv * gv.x;
    v1 *= rinv * gv.y;
    v2 *= rinv * gv.z;
    v3 *= rinv * gv.w;

    const int i0 = (base & 63) >> 1;          // pair index within head (even), i0+1 for 2nd pair
    float2 cs = *(const float2*)(fcos + (size_t)srow * 32 + i0);
    float2 sn = *(const float2*)(fsin + (size_t)srow * 32 + i0);
    float ra0 = v0 * cs.x - v1 * sn.x;
    float rb0 = v0 * sn.x + v1 * cs.x;
    float ra1 = v2 * cs.y - v3 * sn.y;
    float rb1 = v2 * sn.y + v3 * cs.y;
    ushort4 o;
    o.x = f2bf(ra0); o.y = f2bf(rb0); o.z = f2bf(ra1); o.w = f2bf(rb1);
    *(ushort4*)(hp + base) = o;
}

// ---------------- dilated sliding-window attention ----------------
// grid: (68 query-tiles of 64, 16 heads, 2 streams). Block 256 = thread (tq=tid>>4, tk=tid&15).
// Phase A: scores for queries 4tq..+3 x keys 4tk..+3 ; Phase B: same thread owns dims 4tk..+3.
// P stays in registers; cross-lane move via __shfl within the 16-lane tq-group.
__global__ __launch_bounds__(256) void attn(const unsigned short* __restrict__ qkv,
                                            unsigned short* __restrict__ ob) {
    __shared__ float Qs[64][65];
    __shared__ float Ks[64][65];
    __shared__ float Vs[64][64];

    const int qt = blockIdx.x;
    const int head = blockIdx.y;
    const int d = blockIdx.z;
    const int tid = threadIdx.x;
    const int lane = tid & 63;
    const int tq = tid >> 4;
    const int tk = tid & 15;

    const unsigned short* qb = qkv;
    const unsigned short* kb = qkv + (size_t)S_ORIG * DIM;
    const unsigned short* vb = qkv + (size_t)2 * S_ORIG * DIM;

    const int q0 = qt * 64;
    const int og0 = (q0 >> 8) * 512 + d * 256 + (q0 & 255);   // dilation map

    for (int e = tid; e < 4096; e += 256) {
        int row = e >> 6, col = e & 63;
        Qs[row][col] = bf2f(qb[(size_t)(og0 + row) * DIM + head * HD + col]) * 0.125f;
    }

    float m[4], l[4], oacc[4][4];
#pragma unroll
    for (int i = 0; i < 4; i++) {
        m[i] = -1e30f;
        l[i] = 0.0f;
#pragma unroll
        for (int j = 0; j < 4; j++) oacc[i][j] = 0.0f;
    }

    const int kt_lo = (qt - 8 > 0) ? (qt - 8) : 0;
    const int kt_hi = (qt + 8 < 71) ? (qt + 8) : 71;   // tiles 68..71 = zero padding keys (valid, score 0)

    for (int kt = kt_lo; kt <= kt_hi; kt++) {
        const int kbase = kt * 64;
        __syncthreads();   // previous tile's readers done before overwrite (also covers Qs on 1st iter)
        for (int e = tid; e < 4096; e += 256) {
            int row = e >> 6, col = e & 63;
            int kj = kbase + row;
            int ok = (kj >> 8) * 512 + d * 256 + (kj & 255);
            float kvv = 0.0f, vvv = 0.0f;
            if (ok < S_ORIG) {
                kvv = bf2f(kb[(size_t)ok * DIM + head * HD + col]);
                vvv = bf2f(vb[(size_t)ok * DIM + head * HD + col]);
            }
            Ks[row][col] = kvv;
            Vs[row][col] = vvv;
        }
        __syncthreads();

        // Phase A: 4x4 scores
        float s[4][4];
#pragma unroll
        for (int i = 0; i < 4; i++)
#pragma unroll
            for (int j = 0; j < 4; j++) s[i][j] = 0.0f;
#pragma unroll 8
        for (int dd = 0; dd < 64; dd++) {
            float qv[4], kv[4];
#pragma unroll
            for (int i = 0; i < 4; i++) qv[i] = Qs[tq * 4 + i][dd];
#pragma unroll
            for (int j = 0; j < 4; j++) kv[j] = Ks[tk * 4 + j][dd];
#pragma unroll
            for (int i = 0; i < 4; i++)
#pragma unroll
                for (int j = 0; j < 4; j++) s[i][j] = fmaf(qv[i], kv[j], s[i][j]);
        }

        // mask |qi-kj|<=512 (dilated coords), online softmax update (per-thread redundant state)
        float alpha[4];
#pragma unroll
        for (int i = 0; i < 4; i++) {
            const int qi = q0 + tq * 4 + i;
#pragma unroll
            for (int j = 0; j < 4; j++) {
                const int kj = kbase + tk * 4 + j;
                const int dlt = qi - kj;
                if (dlt > WIN || dlt < -WIN) s[i][j] = -1e9f;
            }
            float mx = fmaxf(fmaxf(s[i][0], s[i][1]), fmaxf(s[i][2], s[i][3]));
#pragma unroll
            for (int off = 1; off < 16; off <<= 1) mx = fmaxf(mx, __shfl_xor(mx, off, 64));
            const float mnew = fmaxf(m[i], mx);
            alpha[i] = __expf(m[i] - mnew);
            float sm = 0.0f;
#pragma unroll
            for (int j = 0; j < 4; j++) {
                const float p = __expf(s[i][j] - mnew);
                s[i][j] = p;
                sm += p;
            }
#pragma unroll
            for (int off = 1; off < 16; off <<= 1) sm += __shfl_xor(sm, off, 64);
            m[i] = mnew;
            l[i] = l[i] * alpha[i] + sm;
#pragma unroll
            for (int j = 0; j < 4; j++) oacc[i][j] *= alpha[i];
        }

        // Phase B: o[q][dim] += P[q][kk] * V[kk][dim]; P via shuffle from tq-group lanes
        for (int kk4 = 0; kk4 < 16; kk4++) {
            const int src = (lane & 48) | kk4;
#pragma unroll
            for (int c = 0; c < 4; c++) {
                const int kk = kk4 * 4 + c;
                float pv[4];
#pragma unroll
                for (int i = 0; i < 4; i++) pv[i] = __shfl(s[i][c], src, 64);
                float vv[4];
#pragma unroll
                for (int j = 0; j < 4; j++) vv[j] = Vs[kk][tk * 4 + j];
#pragma unroll
                for (int i = 0; i < 4; i++)
#pragma unroll
                    for (int j = 0; j < 4; j++) oacc[i][j] = fmaf(pv[i], vv[j], oacc[i][j]);
            }
        }
    }

    // finalize: divide by l, write bf16 at original coordinates
#pragma unroll
    for (int i = 0; i < 4; i++) {
        const float linv = 1.0f / l[i];
        const int orow = og0 + tq * 4 + i;
#pragma unroll
        for (int j = 0; j < 4; j++) {
            ob[(size_t)orow * DIM + head * HD + tk * 4 + j] = f2bf(oacc[i][j] * linv);
        }
    }
}

// ---------------- launch ----------------
extern "C" void kernel_launch(void* const* d_in, const int* in_sizes, int n_in,
                              void* d_out, int out_size, void* d_ws, size_t ws_size,
                              hipStream_t stream) {
    const float* x    = (const float*)d_in[0];
    const float* fcos = (const float*)d_in[1];
    const float* fsin = (const float*)d_in[2];
    const float* wq   = (const float*)d_in[3];
    const float* bq   = (const float*)d_in[4];
    const float* wk   = (const float*)d_in[5];
    const float* bk   = (const float*)d_in[6];
    const float* wv   = (const float*)d_in[7];
    const float* bv   = (const float*)d_in[8];
    const float* wo   = (const float*)d_in[9];
    const float* bo   = (const float*)d_in[10];
    const float* gq   = (const float*)d_in[11];
    const float* gk   = (const float*)d_in[12];
    // d_in[13] = f, d_in[14] = L : constants folded (L=256, w=512)

    // workspace layout (bytes):
    //   xb  @ 0          : bf16 x            [8704,1024]         17,825,792
    //   wt  @ 17825792   : bf16 W^T          [4][1024][1024]      8,388,608
    //   h   @ 26214400   : bf16 q/k/v planes [3][8704,1024]      53,477,376
    //   ob  @ 79691776   : bf16 attn out     [8704,1024]         17,825,792   (total ~93 MB)
    char* ws = (char*)d_ws;
    unsigned short* xb = (unsigned short*)(ws);
    unsigned short* wt = (unsigned short*)(ws + 17825792);
    unsigned short* h  = (unsigned short*)(ws + 26214400);
    unsigned short* ob = (unsigned short*)(ws + 79691776);
    float* outp = (float*)d_out;

    cvt_x<<<8704, 256, 0, stream>>>(x, xb);
    transpose_w<<<dim3(16, 16, 4), 256, 0, stream>>>(wq, wk, wv, wo, wt);
    gemm_bf16<0><<<dim3(8, 68, 3), 256, 0, stream>>>(xb, wt, bq, bk, bv, (void*)h);
    norm_rope<<<dim3(8704, 2), 256, 0, stream>>>(h, h + (size_t)S_ORIG * DIM, gq, gk, fcos, fsin);
    attn<<<dim3(68, 16, 2), 256, 0, stream>>>(h, ob);
    gemm_bf16<1><<<dim3(8, 68, 1), 256, 0, stream>>>(ob, wt + (size_t)3 * DIM * DIM, bo, bo, bo, (void*)outp);
}

// Round 2
// 406.926 us; speedup vs baseline: 3.2076x; 3.2076x over previous
//
#include <hip/hip_runtime.h>
#include <hip/hip_bf16.h>
#include <stdint.h>

// Problem constants (shapes fixed by the reference)
#define DIM 1024
#define NH 16
#define HD 64
#define S_ORIG 8704
#define WIN 512          // L * WINDOW = 256*2

typedef __attribute__((ext_vector_type(8))) short short8;
typedef __attribute__((ext_vector_type(4))) float f32x4;

__device__ __forceinline__ float bf2f(unsigned short u) {
    return __uint_as_float(((unsigned int)u) << 16);
}
__device__ __forceinline__ unsigned short f2bf(float f) {
    unsigned int x = __float_as_uint(f);
    unsigned int r = x + 0x7fffu + ((x >> 16) & 1u);   // RNE
    return (unsigned short)(r >> 16);
}

#define GLD_LDS(gptr, lptr) \
    __builtin_amdgcn_global_load_lds((const __attribute__((address_space(1))) void*)(gptr), \
                                     (__attribute__((address_space(3))) void*)(lptr), 16, 0, 0)

// ---------------- fp32 -> bf16 convert (x) ----------------
__global__ __launch_bounds__(256) void cvt_x(const float* __restrict__ x,
                                             unsigned short* __restrict__ xb) {
    int i = (blockIdx.x * 256 + threadIdx.x) * 4;   // total = 8704*1024, exact
    float4 v = *(const float4*)(x + i);
    ushort4 o;
    o.x = f2bf(v.x); o.y = f2bf(v.y); o.z = f2bf(v.z); o.w = f2bf(v.w);
    *(ushort4*)(xb + i) = o;
}

// ---------------- weight transpose + convert: Wt[n][k] = bf16(W[k][n]) ----------------
__global__ __launch_bounds__(256) void transpose_w(const float* __restrict__ w0,
                                                   const float* __restrict__ w1,
                                                   const float* __restrict__ w2,
                                                   const float* __restrict__ w3,
                                                   unsigned short* __restrict__ wt) {
    __shared__ float ts[64][65];
    const int z = blockIdx.z;
    const float* w = z == 0 ? w0 : z == 1 ? w1 : z == 2 ? w2 : w3;
    unsigned short* o = wt + (size_t)z * DIM * DIM;
    const int kb = blockIdx.x * 64, nb = blockIdx.y * 64;
    const int t = threadIdx.x, c = t & 63, r4 = t >> 6;
#pragma unroll
    for (int rr = 0; rr < 16; rr++) {
        int row = rr * 4 + r4;
        ts[row][c] = w[(size_t)(kb + row) * DIM + nb + c];
    }
    __syncthreads();
#pragma unroll
    for (int rr = 0; rr < 16; rr++) {
        int nl = rr * 4 + r4;
        o[(size_t)(nb + nl) * DIM + kb + c] = f2bf(ts[c][nl]);
    }
}

// ---------------- bf16 MFMA GEMM: C[M,N] = A[M,K] * Bt[N,K]^T + bias ----------------
// 128x128 tile, 4 waves, BK=32, global_load_lds width-16 staging (m97 pattern).
template <int OUTF32>
__global__ __launch_bounds__(256) void gemm_bf16(const unsigned short* __restrict__ A,
                                                 const unsigned short* __restrict__ Bt,
                                                 const float* __restrict__ b0,
                                                 const float* __restrict__ b1,
                                                 const float* __restrict__ b2,
                                                 void* __restrict__ Cout) {
    __shared__ __align__(16) unsigned short As[128 * 32];
    __shared__ __align__(16) unsigned short Bs[128 * 32];
    const int z = blockIdx.z;
    const unsigned short* B = Bt + (size_t)z * DIM * DIM;
    const float* bias = z == 0 ? b0 : (z == 1 ? b1 : b2);
    const int m0 = blockIdx.y * 128, n0 = blockIdx.x * 128;
    const int tid = threadIdx.x;
    const int lane = tid & 63, wv = tid >> 6;
    const int wr = wv >> 1, wc = wv & 1;
    const int quad = lane >> 4, r = lane & 15;

    f32x4 acc[4][4];
#pragma unroll
    for (int i = 0; i < 4; i++)
#pragma unroll
        for (int j = 0; j < 4; j++)
#pragma unroll
            for (int t4 = 0; t4 < 4; t4++) acc[i][j][t4] = 0.0f;

    const unsigned short* a_base = A + (size_t)m0 * DIM;
    const unsigned short* b_base = B + (size_t)n0 * DIM;
    // chunk c (16B): row = c>>2, col = (c&3)*8 ; per-wave instr i: c = wv*128 + i*64 + lane
    const int c0 = wv * 128 + lane;
    const int r0 = c0 >> 2, o0 = (c0 & 3) * 8;
    const int c1 = c0 + 64;
    const int r1 = c1 >> 2, o1 = (c1 & 3) * 8;
    unsigned short* lA0 = &As[(size_t)(wv * 128) * 8];
    unsigned short* lA1 = &As[(size_t)(wv * 128 + 64) * 8];
    unsigned short* lB0 = &Bs[(size_t)(wv * 128) * 8];
    unsigned short* lB1 = &Bs[(size_t)(wv * 128 + 64) * 8];

    for (int k0 = 0; k0 < DIM; k0 += 32) {
        __syncthreads();   // previous iteration's readers done before DMA overwrites
        GLD_LDS(a_base + (size_t)r0 * DIM + k0 + o0, lA0);
        GLD_LDS(a_base + (size_t)r1 * DIM + k0 + o1, lA1);
        GLD_LDS(b_base + (size_t)r0 * DIM + k0 + o0, lB0);
        GLD_LDS(b_base + (size_t)r1 * DIM + k0 + o1, lB1);
        __syncthreads();   // compiler emits vmcnt(0) drain here
        short8 af[4], bfr[4];
#pragma unroll
        for (int i = 0; i < 4; i++)
            af[i] = *(const short8*)&As[(wr * 64 + i * 16 + r) * 32 + quad * 8];
#pragma unroll
        for (int j = 0; j < 4; j++)
            bfr[j] = *(const short8*)&Bs[(wc * 64 + j * 16 + r) * 32 + quad * 8];
#pragma unroll
        for (int i = 0; i < 4; i++)
#pragma unroll
            for (int j = 0; j < 4; j++)
                acc[i][j] = __builtin_amdgcn_mfma_f32_16x16x32_bf16(af[i], bfr[j], acc[i][j], 0, 0, 0);
    }

    // epilogue: C/D layout col = lane&15, row = quad*4 + reg
#pragma unroll
    for (int i = 0; i < 4; i++) {
        const int row = m0 + wr * 64 + i * 16 + quad * 4;
#pragma unroll
        for (int j = 0; j < 4; j++) {
            const int col = n0 + wc * 64 + j * 16 + r;
            const float bvl = bias[col];
#pragma unroll
            for (int t4 = 0; t4 < 4; t4++) {
                float vv = acc[i][j][t4] + bvl;
                if (OUTF32) {
                    ((float*)Cout)[(size_t)(row + t4) * DIM + col] = vv;
                } else {
                    ((unsigned short*)Cout)[(size_t)z * S_ORIG * DIM + (size_t)(row + t4) * DIM + col] = f2bf(vv);
                }
            }
        }
    }
}

// ---------------- fused RMSNorm + RoPE (in-place on bf16 plane) ----------------
__global__ __launch_bounds__(256) void norm_rope(unsigned short* __restrict__ hq,
                                                 unsigned short* __restrict__ hk,
                                                 const float* __restrict__ gq,
                                                 const float* __restrict__ gk,
                                                 const float* __restrict__ fcos,
                                                 const float* __restrict__ fsin) {
    const int srow = blockIdx.x;
    const int z = blockIdx.y;
    unsigned short* h = z == 0 ? hq : hk;
    const float* g = z == 0 ? gq : gk;
    const int tid = threadIdx.x;
    const int base = tid * 4;
    unsigned short* hp = h + (size_t)srow * DIM;

    ushort4 raw = *(const ushort4*)(hp + base);
    float v0 = bf2f(raw.x), v1 = bf2f(raw.y), v2 = bf2f(raw.z), v3 = bf2f(raw.w);
    float ss = v0 * v0 + v1 * v1 + v2 * v2 + v3 * v3;
#pragma unroll
    for (int off = 1; off < 64; off <<= 1) ss += __shfl_xor(ss, off, 64);
    __shared__ float red[4];
    if ((tid & 63) == 0) red[tid >> 6] = ss;
    __syncthreads();
    ss = red[0] + red[1] + red[2] + red[3];
    const float rinv = rsqrtf(ss * (1.0f / DIM) + 1e-6f);

    float4 gv = *(const float4*)(g + base);
    v0 *= rinv * gv.x;
    v1 *= rinv * gv.y;
    v2 *= rinv * gv.z;
    v3 *= rinv * gv.w;

    const int i0 = (base & 63) >> 1;
    float2 cs = *(const float2*)(fcos + (size_t)srow * 32 + i0);
    float2 sn = *(const float2*)(fsin + (size_t)srow * 32 + i0);
    float ra0 = v0 * cs.x - v1 * sn.x;
    float rb0 = v0 * sn.x + v1 * cs.x;
    float ra1 = v2 * cs.y - v3 * sn.y;
    float rb1 = v2 * sn.y + v3 * cs.y;
    ushort4 o;
    o.x = f2bf(ra0); o.y = f2bf(rb0); o.z = f2bf(ra1); o.w = f2bf(rb1);
    *(ushort4*)(hp + base) = o;
}

// ---------------- dilated sliding-window attention, MFMA flash-style ----------------
// grid: (68 qtiles of 64, 16 heads, 2 streams), 4 waves; wave owns 16 queries.
// Q frags in registers (pre-scaled). K staged [kk][d] (B-frag QK), V staged transposed
// [d][kk] (B-frag PV). P round-trips through per-wave LDS strip in A-layout.
__global__ __launch_bounds__(256) void attn(const unsigned short* __restrict__ qkv,
                                            unsigned short* __restrict__ ob) {
    __shared__ __align__(16) unsigned short Ks[64 * 72];
    __shared__ __align__(16) unsigned short Vt[64 * 72];
    __shared__ __align__(16) unsigned short Ps[4][16 * 72];

    const int qt = blockIdx.x;
    const int head = blockIdx.y;
    const int d = blockIdx.z;
    const int tid = threadIdx.x;
    const int lane = tid & 63, wv = tid >> 6;
    const int quad = lane >> 4, r16 = lane & 15;

    const unsigned short* qb = qkv;
    const unsigned short* kb = qkv + (size_t)S_ORIG * DIM;
    const unsigned short* vb = qkv + (size_t)2 * S_ORIG * DIM;

    // --- load Q fragment into registers, scaled by 1/sqrt(64) = 0.125 ---
    const int qi_frag = qt * 64 + wv * 16 + r16;
    const int og_q = ((qi_frag >> 8) << 9) + d * 256 + (qi_frag & 255);
    short8 qf[2];
    {
        const unsigned short* qrow = qb + (size_t)og_q * DIM + head * HD + quad * 8;
#pragma unroll
        for (int c = 0; c < 2; c++) {
            union { int4 i4; unsigned short u[8]; short8 s8; } in, outv;
            in.i4 = *(const int4*)(qrow + c * 32);
#pragma unroll
            for (int j = 0; j < 8; j++) outv.u[j] = f2bf(bf2f(in.u[j]) * 0.125f);
            qf[c] = outv.s8;
        }
    }

    f32x4 oacc[4];     // [dim ntile][reg]: col = nt*16+r16, row = quad*4+reg
    float m[4], l[4];
#pragma unroll
    for (int nt = 0; nt < 4; nt++)
#pragma unroll
        for (int rr = 0; rr < 4; rr++) oacc[nt][rr] = 0.0f;
#pragma unroll
    for (int rr = 0; rr < 4; rr++) { m[rr] = -1e30f; l[rr] = 0.0f; }

    const int kt_lo = (qt - 8 > 0) ? (qt - 8) : 0;
    const int kt_hi = (qt + 8 < 71) ? (qt + 8) : 71;   // tiles 68..71 = zero pad keys

    const int qrow0 = qt * 64 + wv * 16 + quad * 4;

    for (int kt = kt_lo; kt <= kt_hi; kt++) {
        const int kbase = kt * 64;
        __syncthreads();   // previous tile's frag readers done before overwrite

        // stage K: [kk][d], rows padded to 72 bf16
        for (int cc = tid; cc < 512; cc += 256) {
            const int row = cc >> 3, ch = cc & 7;
            const int kj = kbase + row;
            const int ok = ((kj >> 8) << 9) + d * 256 + (kj & 255);
            int4 val = {0, 0, 0, 0};
            if (ok < S_ORIG) val = *(const int4*)(kb + (size_t)ok * DIM + head * HD + ch * 8);
            *(int4*)&Ks[row * 72 + ch * 8] = val;
        }
        // stage V transposed: Vt[d][kk], paired u32 writes
        {
            const int kk = (tid & 31) * 2, d0 = (tid >> 5) * 8;
            const int kj0 = kbase + kk;
            const int ok0 = ((kj0 >> 8) << 9) + d * 256 + (kj0 & 255);
            union { int4 i4; unsigned short u[8]; } a0, a1;
            a0.i4 = (int4){0, 0, 0, 0};
            a1.i4 = (int4){0, 0, 0, 0};
            if (ok0 < S_ORIG) {
                a0.i4 = *(const int4*)(vb + (size_t)ok0 * DIM + head * HD + d0);
                a1.i4 = *(const int4*)(vb + (size_t)(ok0 + 1) * DIM + head * HD + d0);
            }
#pragma unroll
            for (int i = 0; i < 8; i++) {
                unsigned int pack = (unsigned int)a0.u[i] | ((unsigned int)a1.u[i] << 16);
                *(unsigned int*)&Vt[(d0 + i) * 72 + kk] = pack;
            }
        }
        __syncthreads();

        // --- QK^T: S[16q x 64k] via 4 ntiles x 2 kchunks MFMA ---
        f32x4 s[4];
#pragma unroll
        for (int nt = 0; nt < 4; nt++) {
            f32x4 a = {0.0f, 0.0f, 0.0f, 0.0f};
            short8 k0f = *(const short8*)&Ks[(nt * 16 + r16) * 72 + quad * 8];
            short8 k1f = *(const short8*)&Ks[(nt * 16 + r16) * 72 + 32 + quad * 8];
            a = __builtin_amdgcn_mfma_f32_16x16x32_bf16(qf[0], k0f, a, 0, 0, 0);
            a = __builtin_amdgcn_mfma_f32_16x16x32_bf16(qf[1], k1f, a, 0, 0, 0);
            s[nt] = a;
        }

        // --- mask + online softmax (C layout: row=quad*4+reg, col=nt*16+r16) ---
#pragma unroll
        for (int rr = 0; rr < 4; rr++) {
            const int qi = qrow0 + rr;
            float mx = -1e30f;
#pragma unroll
            for (int nt = 0; nt < 4; nt++) {
                const int kj = kbase + nt * 16 + r16;
                const int dl = qi - kj;
                if (dl > WIN || dl < -WIN) s[nt][rr] = -1e9f;
                mx = fmaxf(mx, s[nt][rr]);
            }
#pragma unroll
            for (int off = 1; off < 16; off <<= 1) mx = fmaxf(mx, __shfl_xor(mx, off, 64));
            const float mnew = fmaxf(m[rr], mx);
            const float alpha = __expf(m[rr] - mnew);
            float sm = 0.0f;
#pragma unroll
            for (int nt = 0; nt < 4; nt++) {
                const float p = __expf(s[nt][rr] - mnew);
                s[nt][rr] = p;
                sm += p;
            }
#pragma unroll
            for (int off = 1; off < 16; off <<= 1) sm += __shfl_xor(sm, off, 64);
            m[rr] = mnew;
            l[rr] = l[rr] * alpha + sm;
#pragma unroll
            for (int nt = 0; nt < 4; nt++) oacc[nt][rr] *= alpha;
        }

        // --- P -> LDS (bf16, A-layout strip per wave) ---
        unsigned short* pw = &Ps[wv][0];
#pragma unroll
        for (int rr = 0; rr < 4; rr++)
#pragma unroll
            for (int nt = 0; nt < 4; nt++)
                pw[(quad * 4 + rr) * 72 + nt * 16 + r16] = f2bf(s[nt][rr]);
        __asm__ volatile("s_waitcnt lgkmcnt(0)" ::: "memory");

        // --- PV: O[16q x 64d] += P[16 x 64k] * V[64k x 64d] ---
        short8 pf0 = *(const short8*)&Ps[wv][r16 * 72 + quad * 8];
        short8 pf1 = *(const short8*)&Ps[wv][r16 * 72 + 32 + quad * 8];
#pragma unroll
        for (int nt = 0; nt < 4; nt++) {
            short8 v0f = *(const short8*)&Vt[(nt * 16 + r16) * 72 + quad * 8];
            short8 v1f = *(const short8*)&Vt[(nt * 16 + r16) * 72 + 32 + quad * 8];
            oacc[nt] = __builtin_amdgcn_mfma_f32_16x16x32_bf16(pf0, v0f, oacc[nt], 0, 0, 0);
            oacc[nt] = __builtin_amdgcn_mfma_f32_16x16x32_bf16(pf1, v1f, oacc[nt], 0, 0, 0);
        }
    }

    // --- finalize: divide by l, write bf16 at original coordinates ---
#pragma unroll
    for (int rr = 0; rr < 4; rr++) {
        const float linv = 1.0f / l[rr];
        const int qi = qrow0 + rr;
        const int og = ((qi >> 8) << 9) + d * 256 + (qi & 255);
#pragma unroll
        for (int nt = 0; nt < 4; nt++) {
            ob[(size_t)og * DIM + head * HD + nt * 16 + r16] = f2bf(oacc[nt][rr] * linv);
        }
    }
}

// ---------------- launch ----------------
extern "C" void kernel_launch(void* const* d_in, const int* in_sizes, int n_in,
                              void* d_out, int out_size, void* d_ws, size_t ws_size,
                              hipStream_t stream) {
    const float* x    = (const float*)d_in[0];
    const float* fcos = (const float*)d_in[1];
    const float* fsin = (const float*)d_in[2];
    const float* wq   = (const float*)d_in[3];
    const float* bq   = (const float*)d_in[4];
    const float* wk   = (const float*)d_in[5];
    const float* bk   = (const float*)d_in[6];
    const float* wv   = (const float*)d_in[7];
    const float* bv   = (const float*)d_in[8];
    const float* wo   = (const float*)d_in[9];
    const float* bo   = (const float*)d_in[10];
    const float* gq   = (const float*)d_in[11];
    const float* gk   = (const float*)d_in[12];

    char* ws = (char*)d_ws;
    unsigned short* xb = (unsigned short*)(ws);
    unsigned short* wt = (unsigned short*)(ws + 17825792);
    unsigned short* h  = (unsigned short*)(ws + 26214400);
    unsigned short* ob = (unsigned short*)(ws + 79691776);
    float* outp = (float*)d_out;

    cvt_x<<<8704, 256, 0, stream>>>(x, xb);
    transpose_w<<<dim3(16, 16, 4), 256, 0, stream>>>(wq, wk, wv, wo, wt);
    gemm_bf16<0><<<dim3(8, 68, 3), 256, 0, stream>>>(xb, wt, bq, bk, bv, (void*)h);
    norm_rope<<<dim3(8704, 2), 256, 0, stream>>>(h, h + (size_t)S_ORIG * DIM, gq, gk, fcos, fsin);
    attn<<<dim3(68, 16, 2), 256, 0, stream>>>(h, ob);
    gemm_bf16<1><<<dim3(8, 68, 1), 256, 0, stream>>>(ob, wt + (size_t)3 * DIM * DIM, bo, bo, bo, (void*)outp);
}

// Round 3
// 333.978 us; speedup vs baseline: 3.9082x; 1.2184x over previous
//
#include <hip/hip_runtime.h>
#include <hip/hip_bf16.h>
#include <stdint.h>

// Problem constants (shapes fixed by the reference)
#define DIM 1024
#define NH 16
#define HD 64
#define S_ORIG 8704
#define WIN 512          // L * WINDOW = 256*2

typedef __attribute__((ext_vector_type(8))) short short8;
typedef __attribute__((ext_vector_type(4))) float f32x4;

__device__ __forceinline__ float bf2f(unsigned short u) {
    return __uint_as_float(((unsigned int)u) << 16);
}
__device__ __forceinline__ unsigned short f2bf(float f) {
    unsigned int x = __float_as_uint(f);
    unsigned int r = x + 0x7fffu + ((x >> 16) & 1u);   // RNE
    return (unsigned short)(r >> 16);
}
// pack two fp32 -> bf16x2 (round-half-up; inputs are finite non-negative exp values)
__device__ __forceinline__ unsigned int pkbf(float a, float b) {
    unsigned int ua = (__float_as_uint(a) + 0x8000u) >> 16;
    unsigned int ub = (__float_as_uint(b) + 0x8000u) & 0xffff0000u;
    return ua | ub;
}

#define GLD_LDS(gptr, lptr) \
    __builtin_amdgcn_global_load_lds((const __attribute__((address_space(1))) void*)(gptr), \
                                     (__attribute__((address_space(3))) void*)(lptr), 16, 0, 0)

// ---------------- fp32 -> bf16 convert (x) ----------------
__global__ __launch_bounds__(256) void cvt_x(const float* __restrict__ x,
                                             unsigned short* __restrict__ xb) {
    int i = (blockIdx.x * 256 + threadIdx.x) * 4;   // total = 8704*1024, exact
    float4 v = *(const float4*)(x + i);
    ushort4 o;
    o.x = f2bf(v.x); o.y = f2bf(v.y); o.z = f2bf(v.z); o.w = f2bf(v.w);
    *(ushort4*)(xb + i) = o;
}

// ---------------- weight transpose + convert: Wt[n][k] = bf16(W[k][n]) ----------------
__global__ __launch_bounds__(256) void transpose_w(const float* __restrict__ w0,
                                                   const float* __restrict__ w1,
                                                   const float* __restrict__ w2,
                                                   const float* __restrict__ w3,
                                                   unsigned short* __restrict__ wt) {
    __shared__ float ts[64][65];
    const int z = blockIdx.z;
    const float* w = z == 0 ? w0 : z == 1 ? w1 : z == 2 ? w2 : w3;
    unsigned short* o = wt + (size_t)z * DIM * DIM;
    const int kb = blockIdx.x * 64, nb = blockIdx.y * 64;
    const int t = threadIdx.x, c = t & 63, r4 = t >> 6;
#pragma unroll
    for (int rr = 0; rr < 16; rr++) {
        int row = rr * 4 + r4;
        ts[row][c] = w[(size_t)(kb + row) * DIM + nb + c];
    }
    __syncthreads();
#pragma unroll
    for (int rr = 0; rr < 16; rr++) {
        int nl = rr * 4 + r4;
        o[(size_t)(nb + nl) * DIM + kb + c] = f2bf(ts[c][nl]);
    }
}

// ---------------- bf16 MFMA GEMM: C[M,N] = A[M,K] * Bt[N,K]^T + bias ----------------
// 128x128 tile, 4 waves, BK=32, global_load_lds width-16 staging (m97 pattern).
template <int OUTF32>
__global__ __launch_bounds__(256) void gemm_bf16(const unsigned short* __restrict__ A,
                                                 const unsigned short* __restrict__ Bt,
                                                 const float* __restrict__ b0,
                                                 const float* __restrict__ b1,
                                                 const float* __restrict__ b2,
                                                 void* __restrict__ Cout) {
    __shared__ __align__(16) unsigned short As[128 * 32];
    __shared__ __align__(16) unsigned short Bs[128 * 32];
    const int z = blockIdx.z;
    const unsigned short* B = Bt + (size_t)z * DIM * DIM;
    const float* bias = z == 0 ? b0 : (z == 1 ? b1 : b2);
    const int m0 = blockIdx.y * 128, n0 = blockIdx.x * 128;
    const int tid = threadIdx.x;
    const int lane = tid & 63, wv = tid >> 6;
    const int wr = wv >> 1, wc = wv & 1;
    const int quad = lane >> 4, r = lane & 15;

    f32x4 acc[4][4];
#pragma unroll
    for (int i = 0; i < 4; i++)
#pragma unroll
        for (int j = 0; j < 4; j++)
#pragma unroll
            for (int t4 = 0; t4 < 4; t4++) acc[i][j][t4] = 0.0f;

    const unsigned short* a_base = A + (size_t)m0 * DIM;
    const unsigned short* b_base = B + (size_t)n0 * DIM;
    const int c0 = wv * 128 + lane;
    const int r0 = c0 >> 2, o0 = (c0 & 3) * 8;
    const int c1 = c0 + 64;
    const int r1 = c1 >> 2, o1 = (c1 & 3) * 8;
    unsigned short* lA0 = &As[(size_t)(wv * 128) * 8];
    unsigned short* lA1 = &As[(size_t)(wv * 128 + 64) * 8];
    unsigned short* lB0 = &Bs[(size_t)(wv * 128) * 8];
    unsigned short* lB1 = &Bs[(size_t)(wv * 128 + 64) * 8];

    for (int k0 = 0; k0 < DIM; k0 += 32) {
        __syncthreads();
        GLD_LDS(a_base + (size_t)r0 * DIM + k0 + o0, lA0);
        GLD_LDS(a_base + (size_t)r1 * DIM + k0 + o1, lA1);
        GLD_LDS(b_base + (size_t)r0 * DIM + k0 + o0, lB0);
        GLD_LDS(b_base + (size_t)r1 * DIM + k0 + o1, lB1);
        __syncthreads();
        short8 af[4], bfr[4];
#pragma unroll
        for (int i = 0; i < 4; i++)
            af[i] = *(const short8*)&As[(wr * 64 + i * 16 + r) * 32 + quad * 8];
#pragma unroll
        for (int j = 0; j < 4; j++)
            bfr[j] = *(const short8*)&Bs[(wc * 64 + j * 16 + r) * 32 + quad * 8];
#pragma unroll
        for (int i = 0; i < 4; i++)
#pragma unroll
            for (int j = 0; j < 4; j++)
                acc[i][j] = __builtin_amdgcn_mfma_f32_16x16x32_bf16(af[i], bfr[j], acc[i][j], 0, 0, 0);
    }

#pragma unroll
    for (int i = 0; i < 4; i++) {
        const int row = m0 + wr * 64 + i * 16 + quad * 4;
#pragma unroll
        for (int j = 0; j < 4; j++) {
            const int col = n0 + wc * 64 + j * 16 + r;
            const float bvl = bias[col];
#pragma unroll
            for (int t4 = 0; t4 < 4; t4++) {
                float vv = acc[i][j][t4] + bvl;
                if (OUTF32) {
                    ((float*)Cout)[(size_t)(row + t4) * DIM + col] = vv;
                } else {
                    ((unsigned short*)Cout)[(size_t)z * S_ORIG * DIM + (size_t)(row + t4) * DIM + col] = f2bf(vv);
                }
            }
        }
    }
}

// ---------------- fused RMSNorm + RoPE (in-place on bf16 plane) ----------------
__global__ __launch_bounds__(256) void norm_rope(unsigned short* __restrict__ hq,
                                                 unsigned short* __restrict__ hk,
                                                 const float* __restrict__ gq,
                                                 const float* __restrict__ gk,
                                                 const float* __restrict__ fcos,
                                                 const float* __restrict__ fsin) {
    const int srow = blockIdx.x;
    const int z = blockIdx.y;
    unsigned short* h = z == 0 ? hq : hk;
    const float* g = z == 0 ? gq : gk;
    const int tid = threadIdx.x;
    const int base = tid * 4;
    unsigned short* hp = h + (size_t)srow * DIM;

    ushort4 raw = *(const ushort4*)(hp + base);
    float v0 = bf2f(raw.x), v1 = bf2f(raw.y), v2 = bf2f(raw.z), v3 = bf2f(raw.w);
    float ss = v0 * v0 + v1 * v1 + v2 * v2 + v3 * v3;
#pragma unroll
    for (int off = 1; off < 64; off <<= 1) ss += __shfl_xor(ss, off, 64);
    __shared__ float red[4];
    if ((tid & 63) == 0) red[tid >> 6] = ss;
    __syncthreads();
    ss = red[0] + red[1] + red[2] + red[3];
    const float rinv = rsqrtf(ss * (1.0f / DIM) + 1e-6f);

    float4 gv = *(const float4*)(g + base);
    v0 *= rinv * gv.x;
    v1 *= rinv * gv.y;
    v2 *= rinv * gv.z;
    v3 *= rinv * gv.w;

    const int i0 = (base & 63) >> 1;
    float2 cs = *(const float2*)(fcos + (size_t)srow * 32 + i0);
    float2 sn = *(const float2*)(fsin + (size_t)srow * 32 + i0);
    float ra0 = v0 * cs.x - v1 * sn.x;
    float rb0 = v0 * sn.x + v1 * cs.x;
    float ra1 = v2 * cs.y - v3 * sn.y;
    float rb1 = v2 * sn.y + v3 * cs.y;
    ushort4 o;
    o.x = f2bf(ra0); o.y = f2bf(rb0); o.z = f2bf(ra1); o.w = f2bf(rb1);
    *(ushort4*)(hp + base) = o;
}

// ---------------- dilated sliding-window attention, transposed-MFMA flash ----------------
// grid: (32 = head*2+stream, 68 qtiles of 64). XCD swizzle: consecutive-qt blocks are
// 32 apart in linear id -> same XCD residue -> L2 reuse of overlapping K/V windows.
// S^T = K*Q^T per tile (col = q = lane&15, row = kk): each lane owns ONE query ->
// no per-tile cross-lane reductions; fixed-max softmax (scores bounded ~|s|<=8.4);
// l = per-lane scalar partial, reduced once at the end. P: 4x ds_write_b64.
// Zero-pad key tiles (kt>=68) contribute l += count analytically (V rows are zero).
__global__ __launch_bounds__(256) void attn(const unsigned short* __restrict__ qkv,
                                            unsigned short* __restrict__ ob) {
    __shared__ __align__(16) unsigned short Ks[64 * 72];
    __shared__ __align__(16) unsigned short Vt[64 * 72];
    __shared__ __align__(16) unsigned short Ps[4][16 * 72];

    const int head = blockIdx.x >> 1;
    const int d = blockIdx.x & 1;
    const int qt = blockIdx.y;
    const int tid = threadIdx.x;
    const int lane = tid & 63, wv = tid >> 6;
    const int quad = lane >> 4, r16 = lane & 15;

    const unsigned short* qb = qkv;
    const unsigned short* kb = qkv + (size_t)S_ORIG * DIM;
    const unsigned short* vb = qkv + (size_t)2 * S_ORIG * DIM;

    // --- this lane's query (B-operand of S^T): q = r16 within wave tile ---
    const int qi = qt * 64 + wv * 16 + r16;
    const int og_q = ((qi >> 8) << 9) + d * 256 + (qi & 255);
    short8 qf[2];
    {
        const unsigned short* qrow = qb + (size_t)og_q * DIM + head * HD + quad * 8;
#pragma unroll
        for (int c = 0; c < 2; c++) {
            union { int4 i4; unsigned short u[8]; short8 s8; } in, outv;
            in.i4 = *(const int4*)(qrow + c * 32);
#pragma unroll
            for (int j = 0; j < 8; j++) outv.u[j] = f2bf(bf2f(in.u[j]) * 0.125f);
            qf[c] = outv.s8;
        }
    }

    f32x4 oacc[4];     // O^T: row d_local = quad*4+reg (tile nt), col q = r16
    float lsum = 0.0f;
#pragma unroll
    for (int nt = 0; nt < 4; nt++)
#pragma unroll
        for (int rr = 0; rr < 4; rr++) oacc[nt][rr] = 0.0f;

    // real-key tiles only; kt>=68 are all-zero pad rows handled analytically below
    const int kt_lo = (qt - 8 > 0) ? (qt - 8) : 0;
    const int kt_hi = (qt + 8 < 67) ? (qt + 8) : 67;

    // per-thread staging coords (hoisted)
    const int st_row0 = tid >> 3, st_ch = (tid & 7) * 8;          // K: rows tid>>3, +32
    const int vt_kk = (tid & 31) * 2, vt_d0 = (tid >> 5) * 8;     // V^T

    for (int kt = kt_lo; kt <= kt_hi; kt++) {
        const int kbase = kt * 64;
        __syncthreads();   // previous tile's frag readers done before overwrite

        // stage K [kk][d], rows padded to 72 bf16 (kt<=67 => always in-bounds)
#pragma unroll
        for (int half = 0; half < 2; half++) {
            const int row = st_row0 + half * 32;
            const int kj = kbase + row;
            const int ok = ((kj >> 8) << 9) + d * 256 + (kj & 255);
            *(int4*)&Ks[row * 72 + st_ch] = *(const int4*)(kb + (size_t)ok * DIM + head * HD + st_ch);
        }
        // stage V transposed: Vt[d][kk]
        {
            const int kj0 = kbase + vt_kk;
            const int ok0 = ((kj0 >> 8) << 9) + d * 256 + (kj0 & 255);
            union { int4 i4; unsigned short u[8]; } a0, a1;
            a0.i4 = *(const int4*)(vb + (size_t)ok0 * DIM + head * HD + vt_d0);
            a1.i4 = *(const int4*)(vb + (size_t)(ok0 + 1) * DIM + head * HD + vt_d0);
#pragma unroll
            for (int i = 0; i < 8; i++) {
                unsigned int pack = (unsigned int)a0.u[i] | ((unsigned int)a1.u[i] << 16);
                *(unsigned int*)&Vt[(vt_d0 + i) * 72 + vt_kk] = pack;
            }
        }
        __syncthreads();

        // --- S^T[kk][q]: A-op = K rows, B-op = Q frag ---
        f32x4 sv[4];
#pragma unroll
        for (int nt = 0; nt < 4; nt++) {
            short8 k0f = *(const short8*)&Ks[(nt * 16 + r16) * 72 + quad * 8];
            short8 k1f = *(const short8*)&Ks[(nt * 16 + r16) * 72 + 32 + quad * 8];
            f32x4 a = {0.0f, 0.0f, 0.0f, 0.0f};
            a = __builtin_amdgcn_mfma_f32_16x16x32_bf16(k0f, qf[0], a, 0, 0, 0);
            a = __builtin_amdgcn_mfma_f32_16x16x32_bf16(k1f, qf[1], a, 0, 0, 0);
            sv[nt] = a;
        }

        // --- exp (no max subtraction: scores bounded), window mask on edge tiles only ---
        const bool edge = (kt == qt - 8) || (kt == qt + 8);
        unsigned short* pw = &Ps[wv][0];
#pragma unroll
        for (int nt = 0; nt < 4; nt++) {
            float p[4];
#pragma unroll
            for (int rr = 0; rr < 4; rr++) {
                float e = __expf(sv[nt][rr]);
                if (edge) {
                    const int kj = kbase + nt * 16 + quad * 4 + rr;
                    const int dl = qi - kj;
                    if (dl > WIN || dl < -WIN) e = 0.0f;
                }
                p[rr] = e;
            }
            lsum += (p[0] + p[1]) + (p[2] + p[3]);
            uint2 pk;
            pk.x = pkbf(p[0], p[1]);
            pk.y = pkbf(p[2], p[3]);
            *(uint2*)&pw[r16 * 72 + nt * 16 + quad * 4] = pk;
        }
        __asm__ volatile("s_waitcnt lgkmcnt(0)" ::: "memory");

        // --- O^T += V^T * P^T : A-op = Vt rows, B-op = P frag (A-layout of P) ---
        short8 pf0 = *(const short8*)&pw[r16 * 72 + quad * 8];
        short8 pf1 = *(const short8*)&pw[r16 * 72 + 32 + quad * 8];
#pragma unroll
        for (int nt = 0; nt < 4; nt++) {
            short8 v0f = *(const short8*)&Vt[(nt * 16 + r16) * 72 + quad * 8];
            short8 v1f = *(const short8*)&Vt[(nt * 16 + r16) * 72 + 32 + quad * 8];
            oacc[nt] = __builtin_amdgcn_mfma_f32_16x16x32_bf16(v0f, pf0, oacc[nt], 0, 0, 0);
            oacc[nt] = __builtin_amdgcn_mfma_f32_16x16x32_bf16(v1f, pf1, oacc[nt], 0, 0, 0);
        }
    }

    // --- final l: reduce across the 4 quads (other lanes hold other kk of same q) ---
    lsum += __shfl_xor(lsum, 16, 64);
    lsum += __shfl_xor(lsum, 32, 64);
    // zero-pad keys (dilated pos >= 4352 -> orig >= 8704, K=V=0): score 0 -> exp=1 each
    {
        const int cnt = (qi + WIN < 4607 ? qi + WIN : 4607) - 4351;
        if (cnt > 0) lsum += (float)cnt;
    }
    const float linv = 1.0f / lsum;

    // --- write O: lane owns q = r16; 4 consecutive dims per nt ---
#pragma unroll
    for (int nt = 0; nt < 4; nt++) {
        ushort4 o;
        o.x = f2bf(oacc[nt][0] * linv);
        o.y = f2bf(oacc[nt][1] * linv);
        o.z = f2bf(oacc[nt][2] * linv);
        o.w = f2bf(oacc[nt][3] * linv);
        *(ushort4*)&ob[(size_t)og_q * DIM + head * HD + nt * 16 + quad * 4] = o;
    }
}

// ---------------- launch ----------------
extern "C" void kernel_launch(void* const* d_in, const int* in_sizes, int n_in,
                              void* d_out, int out_size, void* d_ws, size_t ws_size,
                              hipStream_t stream) {
    const float* x    = (const float*)d_in[0];
    const float* fcos = (const float*)d_in[1];
    const float* fsin = (const float*)d_in[2];
    const float* wq   = (const float*)d_in[3];
    const float* bq   = (const float*)d_in[4];
    const float* wk   = (const float*)d_in[5];
    const float* bk   = (const float*)d_in[6];
    const float* wv   = (const float*)d_in[7];
    const float* bv   = (const float*)d_in[8];
    const float* wo   = (const float*)d_in[9];
    const float* bo   = (const float*)d_in[10];
    const float* gq   = (const float*)d_in[11];
    const float* gk   = (const float*)d_in[12];

    char* ws = (char*)d_ws;
    unsigned short* xb = (unsigned short*)(ws);
    unsigned short* wt = (unsigned short*)(ws + 17825792);
    unsigned short* h  = (unsigned short*)(ws + 26214400);
    unsigned short* ob = (unsigned short*)(ws + 79691776);
    float* outp = (float*)d_out;

    cvt_x<<<8704, 256, 0, stream>>>(x, xb);
    transpose_w<<<dim3(16, 16, 4), 256, 0, stream>>>(wq, wk, wv, wo, wt);
    gemm_bf16<0><<<dim3(8, 68, 3), 256, 0, stream>>>(xb, wt, bq, bk, bv, (void*)h);
    norm_rope<<<dim3(8704, 2), 256, 0, stream>>>(h, h + (size_t)S_ORIG * DIM, gq, gk, fcos, fsin);
    attn<<<dim3(32, 68), 256, 0, stream>>>(h, ob);
    gemm_bf16<1><<<dim3(8, 68, 1), 256, 0, stream>>>(ob, wt + (size_t)3 * DIM * DIM, bo, bo, bo, (void*)outp);
}